// Round 5
// baseline (1800.898 us; speedup 1.0000x reference)
//
#include <hip/hip_runtime.h>
#include <hip/hip_bf16.h>
#include <math.h>

typedef unsigned short u16;

#define BB 4
#define CC 512
#define HH 128
#define WW 128
#define PP (HH*WW)   // 16384 spatial positions per batch

#define NEG_BIG (-3.0e38f)

__device__ __forceinline__ float bf2f(u16 u) {
    union { unsigned int i; float f; } v; v.i = ((unsigned int)u) << 16; return v.f;
}
__device__ __forceinline__ u16 f2bf(float f) {
    __hip_bfloat16 h = __float2bfloat16(f);
    u16 u; __builtin_memcpy(&u, &h, 2); return u;
}

template<bool F32>
__device__ __forceinline__ float ldg(const void* p, size_t i) {
    if (F32) return ((const float*)p)[i];
    return bf2f(((const u16*)p)[i]);
}

// ---------------------------------------------------------------------------
// K0: input dtype detection (flag=1 -> fp32).  bf16 array: low u16 of each
// u32 is a genuine bf16 of ~N(0,1) data (exp field in [100,132) ~always).
// fp32 array: low u16 is raw mantissa bits (~12% in range).  4096-word vote.
// Round-4 result: resolved NaN => flag=1 (inputs are fp32).
// ---------------------------------------------------------------------------
__global__ __launch_bounds__(256) void detect_kernel(const void* x, int* flag)
{
    const int t = threadIdx.x;
    const unsigned int* w = (const unsigned int*)x;
    int cnt = 0;
#pragma unroll
    for (int s = 0; s < 16; s++) {
        unsigned int v = w[t * 16 + s];
        int e = (v >> 7) & 0xFF;
        cnt += (e >= 100 && e < 132) ? 1 : 0;
    }
    __shared__ int sh[256];
    sh[t] = cnt;
    __syncthreads();
    for (int o = 128; o; o >>= 1) {
        if (t < o) sh[t] += sh[t + o];
        __syncthreads();
    }
    if (t == 0) *flag = (sh[0] < 2048) ? 1 : 0;
}

// ---------------------------------------------------------------------------
// K1: fused q/k/v projection for ONE batch (x pre-offset per dtype).
//   q_t,k_t fp32 [P][64] position-major; v_t bf16 [P][512]
// Grid (P/128, 5), block 256.
// ---------------------------------------------------------------------------
template<bool F32>
__device__ __forceinline__ void proj_body(
    const void* __restrict__ x,
    const void* __restrict__ Wq, const void* __restrict__ bq,
    const void* __restrict__ Wk, const void* __restrict__ bk,
    const void* __restrict__ Wv, const void* __restrict__ bv,
    float* __restrict__ q_t, float* __restrict__ k_t, u16* __restrict__ v_t,
    float (*Wt)[128], float (*Xt)[128])
{
    const int t  = threadIdx.x;
    const int tx = t & 15;        // p direction
    const int ty = t >> 4;        // o direction
    const int p0 = blockIdx.x * 128;
    const int o0 = blockIdx.y * 128;

    float acc[8][8];
#pragma unroll
    for (int i = 0; i < 8; i++)
#pragma unroll
        for (int j = 0; j < 8; j++) acc[i][j] = 0.f;

    for (int k0 = 0; k0 < CC; k0 += 16) {
#pragma unroll
        for (int s = 0; s < 8; s++) {
            int e = t + 256 * s;
            int oo = e & 127, kk = e >> 7;
            int o = o0 + oo;
            float wv;
            if (o < 64)       wv = ldg<F32>(Wq, (size_t)o * CC + k0 + kk);
            else if (o < 128) wv = ldg<F32>(Wk, (size_t)(o - 64) * CC + k0 + kk);
            else              wv = ldg<F32>(Wv, (size_t)(o - 128) * CC + k0 + kk);
            Wt[kk][oo] = wv;
        }
#pragma unroll
        for (int s = 0; s < 8; s++) {
            int e = t + 256 * s;
            int pp = e & 127, kk = e >> 7;
            Xt[kk][pp] = ldg<F32>(x, (size_t)(k0 + kk) * PP + p0 + pp);
        }
        __syncthreads();
#pragma unroll
        for (int kk = 0; kk < 16; kk++) {
            float a[8], bb[8];
#pragma unroll
            for (int i = 0; i < 8; i++) a[i] = Wt[kk][ty * 8 + i];
#pragma unroll
            for (int j = 0; j < 8; j++) bb[j] = Xt[kk][tx * 8 + j];
#pragma unroll
            for (int i = 0; i < 8; i++)
#pragma unroll
                for (int j = 0; j < 8; j++)
                    acc[i][j] = fmaf(a[i], bb[j], acc[i][j]);
        }
        __syncthreads();
    }

    float bias[8];
#pragma unroll
    for (int i = 0; i < 8; i++) {
        int o = o0 + ty * 8 + i;
        bias[i] = (o < 64) ? ldg<F32>(bq, o)
                : (o < 128) ? ldg<F32>(bk, o - 64)
                : ldg<F32>(bv, o - 128);
    }

#pragma unroll
    for (int j = 0; j < 8; j++) {
        int p = p0 + tx * 8 + j;
        if (o0 == 0) {
            float4 r0 = { acc[0][j] + bias[0], acc[1][j] + bias[1],
                          acc[2][j] + bias[2], acc[3][j] + bias[3] };
            float4 r1 = { acc[4][j] + bias[4], acc[5][j] + bias[5],
                          acc[6][j] + bias[6], acc[7][j] + bias[7] };
            if (ty < 8) {
                float4* dst = (float4*)(q_t + (size_t)p * 64 + ty * 8);
                dst[0] = r0; dst[1] = r1;
            } else {
                float4* dst = (float4*)(k_t + (size_t)p * 64 + (ty - 8) * 8);
                dst[0] = r0; dst[1] = r1;
            }
        } else {
            int ch = o0 - 128 + ty * 8;
            ushort4 u0 = { f2bf(acc[0][j] + bias[0]), f2bf(acc[1][j] + bias[1]),
                           f2bf(acc[2][j] + bias[2]), f2bf(acc[3][j] + bias[3]) };
            ushort4 u1 = { f2bf(acc[4][j] + bias[4]), f2bf(acc[5][j] + bias[5]),
                           f2bf(acc[6][j] + bias[6]), f2bf(acc[7][j] + bias[7]) };
            ushort4* dst = (ushort4*)(v_t + (size_t)p * 512 + ch);
            dst[0] = u0; dst[1] = u1;
        }
    }
}

__global__ __launch_bounds__(256) void proj_kernel(
    const void* x_f32, const void* x_b16,
    const void* Wq, const void* bq, const void* Wk, const void* bk,
    const void* Wv, const void* bv, const int* __restrict__ dflag,
    float* q_t, float* k_t, u16* v_t)
{
    __shared__ float Wt[16][128];
    __shared__ float Xt[16][128];
    if (*dflag)
        proj_body<true >(x_f32, Wq, bq, Wk, bk, Wv, bv, q_t, k_t, v_t, Wt, Xt);
    else
        proj_body<false>(x_b16, Wq, bq, Wk, bk, Wv, bv, q_t, k_t, v_t, Wt, Xt);
}

// ---------------------------------------------------------------------------
// K2: energy_H.  Block per w: E[h][i] = sum_c q[h,w,c]*k[i,w,c]; diag -> NEG_BIG.
// ---------------------------------------------------------------------------
__global__ __launch_bounds__(256) void energyH_kernel(
    const float* __restrict__ q_t, const float* __restrict__ k_t,
    float* __restrict__ attn_f)
{
    const int w = blockIdx.x;
    const int t = threadIdx.x, tx = t & 15, ty = t >> 4;
    __shared__ float Qs[32][128];
    __shared__ float Ks[32][128];
    float acc[8][8];
#pragma unroll
    for (int i = 0; i < 8; i++)
#pragma unroll
        for (int j = 0; j < 8; j++) acc[i][j] = 0.f;

    for (int cb = 0; cb < 2; cb++) {
        const int hh = t >> 1;
        const int cl0 = (t & 1) * 16;
        const int cg0 = cb * 32 + cl0;
        const float4* q4 = (const float4*)(q_t + (size_t)(hh * WW + w) * 64 + cg0);
        const float4* k4 = (const float4*)(k_t + (size_t)(hh * WW + w) * 64 + cg0);
#pragma unroll
        for (int s = 0; s < 4; s++) {
            float4 qv = q4[s], kv = k4[s];
            int c = cl0 + s * 4;
            Qs[c][hh] = qv.x; Qs[c + 1][hh] = qv.y; Qs[c + 2][hh] = qv.z; Qs[c + 3][hh] = qv.w;
            Ks[c][hh] = kv.x; Ks[c + 1][hh] = kv.y; Ks[c + 2][hh] = kv.z; Ks[c + 3][hh] = kv.w;
        }
        __syncthreads();
#pragma unroll 4
        for (int c = 0; c < 32; c++) {
            float a[8], bb[8];
#pragma unroll
            for (int i = 0; i < 8; i++) a[i] = Qs[c][ty * 8 + i];
#pragma unroll
            for (int j = 0; j < 8; j++) bb[j] = Ks[c][tx * 8 + j];
#pragma unroll
            for (int i = 0; i < 8; i++)
#pragma unroll
                for (int j = 0; j < 8; j++)
                    acc[i][j] = fmaf(a[i], bb[j], acc[i][j]);
        }
        __syncthreads();
    }
#pragma unroll
    for (int i = 0; i < 8; i++) {
        int h = ty * 8 + i;
        float* row = attn_f + (size_t)(h * WW + w) * 256;
        float v[8];
#pragma unroll
        for (int j = 0; j < 8; j++) {
            int ic = tx * 8 + j;
            v[j] = (ic == h) ? NEG_BIG : acc[i][j];
        }
        ((float4*)(row + tx * 8))[0] = make_float4(v[0], v[1], v[2], v[3]);
        ((float4*)(row + tx * 8))[1] = make_float4(v[4], v[5], v[6], v[7]);
    }
}

// ---------------------------------------------------------------------------
// K3: energy_W.  Block per h: E[w][j] = sum_c q[h,w,c]*k[h,j,c].
// ---------------------------------------------------------------------------
__global__ __launch_bounds__(256) void energyW_kernel(
    const float* __restrict__ q_t, const float* __restrict__ k_t,
    float* __restrict__ attn_f)
{
    const int h = blockIdx.x;
    const int t = threadIdx.x, tx = t & 15, ty = t >> 4;
    __shared__ float Qs[32][128];
    __shared__ float Ks[32][128];
    float acc[8][8];
#pragma unroll
    for (int i = 0; i < 8; i++)
#pragma unroll
        for (int j = 0; j < 8; j++) acc[i][j] = 0.f;

    for (int cb = 0; cb < 2; cb++) {
        const int ww = t >> 1;
        const int cl0 = (t & 1) * 16;
        const int cg0 = cb * 32 + cl0;
        const float4* q4 = (const float4*)(q_t + (size_t)(h * WW + ww) * 64 + cg0);
        const float4* k4 = (const float4*)(k_t + (size_t)(h * WW + ww) * 64 + cg0);
#pragma unroll
        for (int s = 0; s < 4; s++) {
            float4 qv = q4[s], kv = k4[s];
            int c = cl0 + s * 4;
            Qs[c][ww] = qv.x; Qs[c + 1][ww] = qv.y; Qs[c + 2][ww] = qv.z; Qs[c + 3][ww] = qv.w;
            Ks[c][ww] = kv.x; Ks[c + 1][ww] = kv.y; Ks[c + 2][ww] = kv.z; Ks[c + 3][ww] = kv.w;
        }
        __syncthreads();
#pragma unroll 4
        for (int c = 0; c < 32; c++) {
            float a[8], bb[8];
#pragma unroll
            for (int i = 0; i < 8; i++) a[i] = Qs[c][ty * 8 + i];
#pragma unroll
            for (int j = 0; j < 8; j++) bb[j] = Ks[c][tx * 8 + j];
#pragma unroll
            for (int i = 0; i < 8; i++)
#pragma unroll
                for (int j = 0; j < 8; j++)
                    acc[i][j] = fmaf(a[i], bb[j], acc[i][j]);
        }
        __syncthreads();
    }
#pragma unroll
    for (int i = 0; i < 8; i++) {
        int w = ty * 8 + i;
        float* row = attn_f + (size_t)(h * WW + w) * 256 + 128;
        ((float4*)(row + tx * 8))[0] = make_float4(acc[i][0], acc[i][1], acc[i][2], acc[i][3]);
        ((float4*)(row + tx * 8))[1] = make_float4(acc[i][4], acc[i][5], acc[i][6], acc[i][7]);
    }
}

// ---------------------------------------------------------------------------
// K4: softmax over 256, one wave per row, fp32 -> bf16, finite-guarded.
// ---------------------------------------------------------------------------
__global__ __launch_bounds__(256) void softmax_kernel(
    const float* __restrict__ attn_f, u16* __restrict__ attn_b)
{
    const int wave = threadIdx.x >> 6, lane = threadIdx.x & 63;
    const size_t row = (size_t)blockIdx.x * 4 + wave;
    const float* rp = attn_f + row * 256;
    float4 v = ((const float4*)rp)[lane];
    v.x = isfinite(v.x) ? v.x : NEG_BIG;
    v.y = isfinite(v.y) ? v.y : NEG_BIG;
    v.z = isfinite(v.z) ? v.z : NEG_BIG;
    v.w = isfinite(v.w) ? v.w : NEG_BIG;
    float m = fmaxf(fmaxf(v.x, v.y), fmaxf(v.z, v.w));
#pragma unroll
    for (int off = 32; off; off >>= 1) m = fmaxf(m, __shfl_xor(m, off));
    float e0 = __expf(v.x - m), e1 = __expf(v.y - m);
    float e2 = __expf(v.z - m), e3 = __expf(v.w - m);
    float s = e0 + e1 + e2 + e3;
#pragma unroll
    for (int off = 32; off; off >>= 1) s += __shfl_xor(s, off);
    float inv = 1.0f / s;
    ushort4 u = { f2bf(e0 * inv), f2bf(e1 * inv), f2bf(e2 * inv), f2bf(e3 * inv) };
    ((ushort4*)(attn_b + row * 256))[lane] = u;
}

// ---------------------------------------------------------------------------
// K5: column aggregation.  Block (c-tile, w):
//   out_t[(h*W+w)*512+c] = sum_i v_t[(i*W+w)*512+c] * attnH[(h*W+w)*256+i]
// ---------------------------------------------------------------------------
__global__ __launch_bounds__(256) void aggA_kernel(
    const u16* __restrict__ v_t, const u16* __restrict__ attn_b,
    u16* __restrict__ out_t)
{
    const int c0 = blockIdx.x * 128, w = blockIdx.y;
    const int t = threadIdx.x, tx = t & 15, ty = t >> 4;
    __shared__ float Vs[16][128];
    __shared__ float As[16][132];
    float acc[8][8];
#pragma unroll
    for (int i = 0; i < 8; i++)
#pragma unroll
        for (int j = 0; j < 8; j++) acc[i][j] = 0.f;

    for (int i0 = 0; i0 < HH; i0 += 16) {
#pragma unroll
        for (int s = 0; s < 2; s++) {
            int e = t + 256 * s;
            int cc = (e & 31) * 4, ii = e >> 5;
            ushort4 u = *(const ushort4*)(v_t + (size_t)((i0 + ii) * WW + w) * 512 + c0 + cc);
            Vs[ii][cc + 0] = bf2f(u.x); Vs[ii][cc + 1] = bf2f(u.y);
            Vs[ii][cc + 2] = bf2f(u.z); Vs[ii][cc + 3] = bf2f(u.w);
        }
#pragma unroll
        for (int s = 0; s < 8; s++) {
            int e = t + 256 * s;
            int ii = e & 15, hh = e >> 4;
            As[ii][hh] = bf2f(attn_b[(size_t)(hh * WW + w) * 256 + i0 + ii]);
        }
        __syncthreads();
#pragma unroll
        for (int ii = 0; ii < 16; ii++) {
            float vv[8], aa[8];
#pragma unroll
            for (int ci = 0; ci < 8; ci++) vv[ci] = Vs[ii][tx * 8 + ci];
#pragma unroll
            for (int hj = 0; hj < 8; hj++) aa[hj] = As[ii][ty * 8 + hj];
#pragma unroll
            for (int ci = 0; ci < 8; ci++)
#pragma unroll
                for (int hj = 0; hj < 8; hj++)
                    acc[ci][hj] = fmaf(vv[ci], aa[hj], acc[ci][hj]);
        }
        __syncthreads();
    }
#pragma unroll
    for (int hj = 0; hj < 8; hj++) {
        int h = ty * 8 + hj;
        ushort4 u0 = { f2bf(acc[0][hj]), f2bf(acc[1][hj]), f2bf(acc[2][hj]), f2bf(acc[3][hj]) };
        ushort4 u1 = { f2bf(acc[4][hj]), f2bf(acc[5][hj]), f2bf(acc[6][hj]), f2bf(acc[7][hj]) };
        ushort4* dst = (ushort4*)(out_t + (size_t)(h * WW + w) * 512 + c0 + tx * 8);
        dst[0] = u0; dst[1] = u1;
    }
}

// ---------------------------------------------------------------------------
// K6: row aggregation + fused epilogue (x AND out pre-offset per dtype).
// F32 path writes float output; bf16 path writes bf16 output.
// ---------------------------------------------------------------------------
template<bool F32>
__device__ __forceinline__ void aggB_body(
    const u16* __restrict__ v_t, const u16* __restrict__ attn_b,
    const u16* __restrict__ out_t, const void* __restrict__ x,
    const void* __restrict__ gamma, void* __restrict__ out,
    float (*Vs)[128], float (*As)[132])
{
    const int c0 = blockIdx.x * 128, h = blockIdx.y;
    const int t = threadIdx.x, tx = t & 15, ty = t >> 4;
    float acc[8][8];
#pragma unroll
    for (int i = 0; i < 8; i++)
#pragma unroll
        for (int j = 0; j < 8; j++) acc[i][j] = 0.f;

    for (int j0 = 0; j0 < WW; j0 += 16) {
#pragma unroll
        for (int s = 0; s < 2; s++) {
            int e = t + 256 * s;
            int cc = (e & 31) * 4, jj = e >> 5;
            ushort4 u = *(const ushort4*)(v_t + (size_t)(h * WW + j0 + jj) * 512 + c0 + cc);
            Vs[jj][cc + 0] = bf2f(u.x); Vs[jj][cc + 1] = bf2f(u.y);
            Vs[jj][cc + 2] = bf2f(u.z); Vs[jj][cc + 3] = bf2f(u.w);
        }
#pragma unroll
        for (int s = 0; s < 8; s++) {
            int e = t + 256 * s;
            int jj = e & 15, ww = e >> 4;
            As[jj][ww] = bf2f(attn_b[(size_t)(h * WW + ww) * 256 + 128 + j0 + jj]);
        }
        __syncthreads();
#pragma unroll
        for (int jj = 0; jj < 16; jj++) {
            float vv[8], aa[8];
#pragma unroll
            for (int ci = 0; ci < 8; ci++) vv[ci] = Vs[jj][tx * 8 + ci];
#pragma unroll
            for (int wj = 0; wj < 8; wj++) aa[wj] = As[jj][ty * 8 + wj];
#pragma unroll
            for (int ci = 0; ci < 8; ci++)
#pragma unroll
                for (int wj = 0; wj < 8; wj++)
                    acc[ci][wj] = fmaf(vv[ci], aa[wj], acc[ci][wj]);
        }
        __syncthreads();
    }
#pragma unroll
    for (int wj = 0; wj < 8; wj++) {
        int w = ty * 8 + wj;
        const ushort4* cp = (const ushort4*)(out_t + (size_t)(h * WW + w) * 512 + c0 + tx * 8);
        ushort4 u0 = cp[0], u1 = cp[1];
        acc[0][wj] += bf2f(u0.x); acc[1][wj] += bf2f(u0.y);
        acc[2][wj] += bf2f(u0.z); acc[3][wj] += bf2f(u0.w);
        acc[4][wj] += bf2f(u1.x); acc[5][wj] += bf2f(u1.y);
        acc[6][wj] += bf2f(u1.z); acc[7][wj] += bf2f(u1.w);
    }
    const float g = ldg<F32>(gamma, 0);
#pragma unroll
    for (int ci = 0; ci < 8; ci++) {
        int c = c0 + tx * 8 + ci;
        size_t base = (size_t)(c * HH + h) * WW + ty * 8;
        float r[8];
#pragma unroll
        for (int k = 0; k < 8; k++)
            r[k] = g * acc[ci][k] + ldg<F32>(x, base + k);
        if (F32) {
            float* op = (float*)out + base;
            ((float4*)op)[0] = make_float4(r[0], r[1], r[2], r[3]);
            ((float4*)op)[1] = make_float4(r[4], r[5], r[6], r[7]);
        } else {
            u16* op = (u16*)out + base;
            ushort4 o0 = { f2bf(r[0]), f2bf(r[1]), f2bf(r[2]), f2bf(r[3]) };
            ushort4 o1 = { f2bf(r[4]), f2bf(r[5]), f2bf(r[6]), f2bf(r[7]) };
            *(ushort4*)(op) = o0;
            *(ushort4*)(op + 4) = o1;
        }
    }
}

__global__ __launch_bounds__(256) void aggB_kernel(
    const u16* v_t, const u16* attn_b, const u16* out_t,
    const void* x_f32, const void* x_b16, const void* gamma,
    const int* __restrict__ dflag, void* out_f32, void* out_b16)
{
    __shared__ float Vs[16][128];
    __shared__ float As[16][132];
    if (*dflag)
        aggB_body<true >(v_t, attn_b, out_t, x_f32, gamma, out_f32, Vs, As);
    else
        aggB_body<false>(v_t, attn_b, out_t, x_b16, gamma, out_b16, Vs, As);
}

// ---------------------------------------------------------------------------
extern "C" void kernel_launch(void* const* d_in, const int* in_sizes, int n_in,
                              void* d_out, int out_size, void* d_ws, size_t ws_size,
                              hipStream_t stream)
{
    const void* x     = d_in[0];
    const void* Wq    = d_in[1];
    const void* bq    = d_in[2];
    const void* Wk    = d_in[3];
    const void* bk    = d_in[4];
    const void* Wv    = d_in[5];
    const void* bv    = d_in[6];
    const void* gamma = d_in[7];

    // per-batch workspace (~40 MiB peak) with dead-buffer reuse:
    //   [0,256)B dflag | q_t fp32 4MiB | k_t fp32 4MiB | v_t bf16 16MiB |
    //   attn_f fp32 16MiB.  attn_b bf16 8MiB overlays q/k (dead after
    //   energies); out_t bf16 16MiB overlays attn_f (dead after softmax).
    char* ws = (char*)d_ws;
    int*   dflag  = (int*)ws;
    float* q_t    = (float*)(ws + 256);
    float* k_t    = q_t + (size_t)PP * 64;
    u16*   v_t    = (u16*)(k_t + (size_t)PP * 64);
    float* attn_f = (float*)(v_t + (size_t)PP * 512);
    u16*   attn_b = (u16*)q_t;
    u16*   out_t  = (u16*)attn_f;

    detect_kernel<<<dim3(1), 256, 0, stream>>>(x, dflag);

    for (int b = 0; b < BB; b++) {
        const void* x_f = (const void*)((const float*)x + (size_t)b * CC * PP);
        const void* x_h = (const void*)((const u16*)x   + (size_t)b * CC * PP);
        void* o_f = (void*)((float*)d_out + (size_t)b * CC * PP);
        void* o_h = (void*)((u16*)d_out   + (size_t)b * CC * PP);
        proj_kernel<<<dim3(PP / 128, 5), 256, 0, stream>>>(
            x_f, x_h, Wq, bq, Wk, bk, Wv, bv, dflag, q_t, k_t, v_t);
        energyH_kernel<<<dim3(WW), 256, 0, stream>>>(q_t, k_t, attn_f);
        energyW_kernel<<<dim3(HH), 256, 0, stream>>>(q_t, k_t, attn_f);
        softmax_kernel<<<dim3(PP / 4), 256, 0, stream>>>(attn_f, attn_b);
        aggA_kernel<<<dim3(4, WW), 256, 0, stream>>>(v_t, attn_b, out_t);
        aggB_kernel<<<dim3(4, HH), 256, 0, stream>>>(
            v_t, attn_b, out_t, x_f, x_h, gamma, dflag, o_f, o_h);
    }
}